// Round 5
// baseline (73.049 us; speedup 1.0000x reference)
//
#include <hip/hip_runtime.h>

#define SP_EPS 1e-6f
typedef __fp16 h2 __attribute__((ext_vector_type(2)));

// features f32 (V,64) -> fp16 (V,64) in workspace. 4 floats/thread.
__global__ __launch_bounds__(256) void f32_to_f16_kernel(
    const float* __restrict__ in, unsigned* __restrict__ outh, int n4)
{
    int i = blockIdx.x * 256 + threadIdx.x;
    if (i >= n4) return;
    const float4 v = ((const float4*)in)[i];
    h2 p0 = __builtin_amdgcn_cvt_pkrtz(v.x, v.y);
    h2 p1 = __builtin_amdgcn_cvt_pkrtz(v.z, v.w);
    uint2 o;
    o.x = *(unsigned*)&p0;
    o.y = *(unsigned*)&p1;
    ((uint2*)outh)[i] = o;
}

// One wave per vertex; half-wave h processes neighbor 2kk+h; lane j owns the
// feature pair (2j, 2j+1) packed as one dword of the fp16 table.
// FMA directly from packed f16 via v_fma_mix_f32 op_sel (no unpack).
__global__ __launch_bounds__(256) void softpixel_mix_kernel(
    const unsigned short* __restrict__ fb,   // (V, 64) fp16
    const float* __restrict__ distsq,        // (V, 32)
    const int*   __restrict__ nidx,          // (V, 32)
    const float* __restrict__ ls_ptr,
    float*       __restrict__ out,           // (V, 192)
    int V)
{
    __shared__ float4 qbuf[4][32];    // (as_float(idx), w0, w1, w2)
    const int lane = threadIdx.x & 63;
    const int wv   = threadIdx.x >> 6;
    const int v    = blockIdx.x * 4 + wv;
    const int h    = lane >> 5;
    const int j    = lane & 31;
    const int vc   = v < V ? v : V - 1;

    const float ls     = ls_ptr[0];
    const float scaler = 30.0f * ls;          // 10 * ls * SUBDIVISIONS
    const float inv_ls = 1.0f / ls;

    // Both halves compute all 32 neighbor weights (butterfly gives full sums
    // in every lane; only h==0 writes the broadcast buffer).
    const unsigned dvoff = (unsigned)vc * 32u + (unsigned)j;
    const float dsq = distsq[dvoff];
    const int   nb  = nidx[dvoff];
    const float d   = sqrtf(dsq + SP_EPS);
    const float t1  = d - inv_ls;
    const float t2  = d - 2.0f * inv_ls;
    const float w0  = __expf(-scaler * d  * d);
    const float w1  = __expf(-scaler * t1 * t1);
    const float w2  = __expf(-scaler * t2 * t2);
    if (h == 0)
        qbuf[wv][j] = make_float4(__int_as_float(nb), w0, w1, w2);
    __syncthreads();

    float a0l = 0.f, a0h = 0.f, a1l = 0.f, a1h = 0.f, a2l = 0.f, a2h = 0.f;
    const unsigned j4 = (unsigned)(j << 2);

    #pragma unroll
    for (int kk = 0; kk < 16; ++kk) {
        const float4 q = qbuf[wv][2 * kk + h];      // one ds_read_b128 broadcast
        const int    ik = __float_as_int(q.x);
        const unsigned boff = ((unsigned)ik << 7) + j4;   // row*128B + j*4B
        const unsigned fp = *(const unsigned*)((const char*)fb + boff); // 2 f16
        asm("v_fma_mix_f32 %0, %1, %2, %0 op_sel:[0,0,0] op_sel_hi:[0,1,0]"
            : "+v"(a0l) : "v"(q.y), "v"(fp));
        asm("v_fma_mix_f32 %0, %1, %2, %0 op_sel:[0,1,0] op_sel_hi:[0,1,0]"
            : "+v"(a0h) : "v"(q.y), "v"(fp));
        asm("v_fma_mix_f32 %0, %1, %2, %0 op_sel:[0,0,0] op_sel_hi:[0,1,0]"
            : "+v"(a1l) : "v"(q.z), "v"(fp));
        asm("v_fma_mix_f32 %0, %1, %2, %0 op_sel:[0,1,0] op_sel_hi:[0,1,0]"
            : "+v"(a1h) : "v"(q.z), "v"(fp));
        asm("v_fma_mix_f32 %0, %1, %2, %0 op_sel:[0,0,0] op_sel_hi:[0,1,0]"
            : "+v"(a2l) : "v"(q.w), "v"(fp));
        asm("v_fma_mix_f32 %0, %1, %2, %0 op_sel:[0,1,0] op_sel_hi:[0,1,0]"
            : "+v"(a2h) : "v"(q.w), "v"(fp));
    }

    // Denominators: 5-stage butterfly within each 32-lane half (each half
    // computed the full neighbor set, so every lane ends with the full sum).
    float s0 = w0, s1 = w1, s2 = w2;
    #pragma unroll
    for (int st = 1; st < 32; st <<= 1) {
        s0 += __shfl_xor(s0, st, 64);
        s1 += __shfl_xor(s1, st, 64);
        s2 += __shfl_xor(s2, st, 64);
    }
    const float r0 = __builtin_amdgcn_rcpf(s0 + SP_EPS);
    const float r1 = __builtin_amdgcn_rcpf(s1 + SP_EPS);
    const float r2 = __builtin_amdgcn_rcpf(s2 + SP_EPS);

    // Cross-half combine on the VALU pipe: after v_permlane32_swap_b32 A,B:
    // A' = {A.lo, B.lo}, B' = {A.hi, B.hi}; A'+B' = lanes<32: full A sum,
    // lanes>=32: full B sum. Lanes>=32 then own the odd feature column.
    asm("v_permlane32_swap_b32 %0, %1" : "+v"(a0l), "+v"(a0h));
    asm("v_permlane32_swap_b32 %0, %1" : "+v"(a1l), "+v"(a1h));
    asm("v_permlane32_swap_b32 %0, %1" : "+v"(a2l), "+v"(a2h));
    const float c0 = a0l + a0h;   // lanes<32: feat 2j ; lanes>=32: feat 2j+1
    const float c1 = a1l + a1h;
    const float c2 = a2l + a2h;

    if (v < V) {
        float* o = out + (unsigned)v * 192u + (unsigned)((j << 1) + h);
        o[0]   = c0 * r0;
        o[64]  = c1 * r1;
        o[128] = c2 * r2;
    }
}

// Fallback (fp32 gather) if workspace can't hold the fp16 feature table.
__global__ __launch_bounds__(256) void softpixel_f32_kernel(
    const float* __restrict__ feat,
    const float* __restrict__ distsq,
    const int*   __restrict__ nidx,
    const float* __restrict__ ls_ptr,
    float*       __restrict__ out,
    int V)
{
    const int lane = threadIdx.x & 63;
    const int wv   = threadIdx.x >> 6;
    const int v    = blockIdx.x * 4 + wv;
    if (v >= V) return;

    const float ls     = ls_ptr[0];
    const float scaler = 30.0f * ls;
    const float inv_ls = 1.0f / ls;

    float w0 = 0.f, w1 = 0.f, w2 = 0.f;
    int nb = 0;
    if (lane < 32) {
        const float dsq = distsq[v * 32 + lane];
        nb = nidx[v * 32 + lane];
        const float d  = sqrtf(dsq + SP_EPS);
        const float t1 = d - inv_ls;
        const float t2 = d - 2.0f * inv_ls;
        w0 = __expf(-scaler * d  * d);
        w1 = __expf(-scaler * t1 * t1);
        w2 = __expf(-scaler * t2 * t2);
    }

    float a0 = 0.f, a1 = 0.f, a2 = 0.f;
    float s0 = SP_EPS, s1 = SP_EPS, s2 = SP_EPS;
    #pragma unroll
    for (int k = 0; k < 32; ++k) {
        const int   ik = __shfl(nb, k, 64);
        const float u0 = __shfl(w0, k, 64);
        const float u1 = __shfl(w1, k, 64);
        const float u2 = __shfl(w2, k, 64);
        const float f  = feat[(size_t)ik * 64 + lane];
        a0 = fmaf(u0, f, a0);
        a1 = fmaf(u1, f, a1);
        a2 = fmaf(u2, f, a2);
        s0 += u0; s1 += u1; s2 += u2;
    }
    float* o = out + (size_t)v * 192 + lane;
    o[0]   = a0 / s0;
    o[64]  = a1 / s1;
    o[128] = a2 / s2;
}

extern "C" void kernel_launch(void* const* d_in, const int* in_sizes, int n_in,
                              void* d_out, int out_size, void* d_ws, size_t ws_size,
                              hipStream_t stream) {
    const float* feat   = (const float*)d_in[0];   // (V, 64)
    const float* distsq = (const float*)d_in[1];   // (V, 32)
    const int*   nidx   = (const int*)d_in[2];     // (V, 32)
    const float* ls     = (const float*)d_in[3];   // scalar

    const int V = in_sizes[1] / 32;
    const int F = in_sizes[0] / V;                 // 64
    float* out = (float*)d_out;

    const size_t need = (size_t)V * F * sizeof(unsigned short);
    const int grid = (V + 3) / 4;                  // 4 vertices (waves) / block

    if ((size_t)ws_size >= need && F == 64) {
        unsigned* fh = (unsigned*)d_ws;
        const int n4 = V * F / 4;
        f32_to_f16_kernel<<<(n4 + 255) / 256, 256, 0, stream>>>(feat, fh, n4);
        softpixel_mix_kernel<<<grid, 256, 0, stream>>>(
            (const unsigned short*)fh, distsq, nidx, ls, out, V);
    } else {
        softpixel_f32_kernel<<<grid, 256, 0, stream>>>(feat, distsq, nidx, ls, out, V);
    }
}